// Round 1
// baseline (572.885 us; speedup 1.0000x reference)
//
#include <hip/hip_runtime.h>
#include <hip/hip_bf16.h>
#include <math.h>

// Problem constants (from reference): x[16384][512], y[2048][5][512], out[16384][2048]
#define QTOT 16384
#define CDIM 2048
#define DDIM 512
#define SDIM 5

#define QB 16          // query rows per block
#define NT 512         // threads per block (8 waves)
#define KK 2           // k-slice per stage
#define NSTAGE (DDIM / KK)   // 256 stages

// ---------------------------------------------------------------------------
// async global->LDS, 16B per lane (wave-uniform LDS base + lane*16)
__device__ __forceinline__ void gload_lds16(const float* g, float* l) {
  __builtin_amdgcn_global_load_lds(
      (const __attribute__((address_space(1))) void*)g,
      (__attribute__((address_space(3))) void*)l, 16, 0, 0);
}

// ---------------------------------------------------------------------------
// Kernel 1: Bt[k][c] = mean_s y[c][s][k]   (transposed prototypes, 512x2048)
// 64x64 tile transpose through LDS; coalesced on both sides.
__global__ void __launch_bounds__(256)
proto_kernel(const float* __restrict__ y, float* __restrict__ bt) {
  __shared__ float tile[64][65];   // +1 pad: conflict-free transpose
  const int t  = threadIdx.x;
  const int c0 = blockIdx.x * 64;  // 32 blocks
  const int k0 = blockIdx.y * 64;  // 8 blocks

  #pragma unroll
  for (int i = 0; i < 16; ++i) {
    int idx = t + 256 * i;
    int cl = idx >> 6, kl = idx & 63;
    const float* p = y + (size_t)(c0 + cl) * (SDIM * DDIM) + (k0 + kl);
    float s = 0.f;
    #pragma unroll
    for (int ss = 0; ss < SDIM; ++ss) s += p[ss * DDIM];
    tile[cl][kl] = s * 0.2f;
  }
  __syncthreads();
  #pragma unroll
  for (int i = 0; i < 16; ++i) {
    int idx = t + 256 * i;
    int kl = idx >> 6, cl = idx & 63;
    bt[(size_t)(k0 + kl) * CDIM + (c0 + cl)] = tile[cl][kl];
  }
}

// ---------------------------------------------------------------------------
// Kernel 2: fused GEMM (d = x @ Bt) + row softmax.
// Block: 16 rows x all 2048 cols. Thread micro-tile: 8 rows x 8 cols (64 acc).
// tr = t/256 selects row-half (rows tr*8..tr*8+7); tc = t%256 selects cols
// {tc*4..tc*4+3} and {1024+tc*4..1024+tc*4+3}  -> all LDS reads lane-contiguous.
__global__ void __launch_bounds__(NT)
gemm_softmax_kernel(const float* __restrict__ x,
                    const float* __restrict__ bt,
                    float* __restrict__ out) {
  __shared__ float lds_a[QB * DDIM];        // 32 KB, A[r][k] row-major
  __shared__ float lds_b[2][KK * CDIM];     // 2 x 16 KB double buffer, [kq][c]

  const int t    = threadIdx.x;
  const int lane = t & 63;
  const int wav  = t >> 6;          // 0..7
  const int tr   = t >> 8;          // 0..1
  const int tc   = t & 255;         // 0..255
  const int q0   = blockIdx.x * QB;

  // ---- stage A once (coalesced float4; one-time cost) ----
  {
    const float4* src = (const float4*)(x + (size_t)q0 * DDIM);
    float4* dst = (float4*)lds_a;
    #pragma unroll
    for (int m = 0; m < 4; ++m) dst[t + NT * m] = src[t + NT * m];
  }
  // ---- stage B buffer 0 (kt = 0) ----
  {
    #pragma unroll
    for (int m = 0; m < 2; ++m) {
      int f = t + NT * m;           // 1024 float4 = 4096 floats = KK*CDIM
      gload_lds16(bt + f * 4, &lds_b[0][f * 4]);
    }
  }
  __syncthreads();   // drains vmcnt(0): A + B0 visible

  float acc[64];
  #pragma unroll
  for (int i = 0; i < 64; ++i) acc[i] = 0.f;

  const int r0 = tr * 8;
  const int cA = tc * 4;

  int cur = 0;
  for (int kt = 0; kt < NSTAGE; ++kt) {
    // prefetch next k-slice into the other buffer (in flight across compute)
    if (kt + 1 < NSTAGE) {
      const float* src = bt + (size_t)(kt + 1) * (KK * CDIM);
      #pragma unroll
      for (int m = 0; m < 2; ++m) {
        int f = t + NT * m;
        gload_lds16(src + f * 4, &lds_b[cur ^ 1][f * 4]);
      }
    }
    // A fragments: broadcast b64 reads (all lanes of a wave share tr)
    float a0[8], a1[8];
    #pragma unroll
    for (int r = 0; r < 8; ++r) {
      float2 av = *(const float2*)&lds_a[(r0 + r) * DDIM + kt * KK];
      a0[r] = av.x; a1[r] = av.y;
    }
    // B fragments: lane-contiguous b128 reads (conflict-free)
    const float4 b00 = *(const float4*)&lds_b[cur][cA];
    const float4 b01 = *(const float4*)&lds_b[cur][1024 + cA];
    const float4 b10 = *(const float4*)&lds_b[cur][CDIM + cA];
    const float4 b11 = *(const float4*)&lds_b[cur][CDIM + 1024 + cA];
    #pragma unroll
    for (int r = 0; r < 8; ++r) {
      acc[r*8+0] = fmaf(a0[r], b00.x, acc[r*8+0]);
      acc[r*8+1] = fmaf(a0[r], b00.y, acc[r*8+1]);
      acc[r*8+2] = fmaf(a0[r], b00.z, acc[r*8+2]);
      acc[r*8+3] = fmaf(a0[r], b00.w, acc[r*8+3]);
      acc[r*8+4] = fmaf(a0[r], b01.x, acc[r*8+4]);
      acc[r*8+5] = fmaf(a0[r], b01.y, acc[r*8+5]);
      acc[r*8+6] = fmaf(a0[r], b01.z, acc[r*8+6]);
      acc[r*8+7] = fmaf(a0[r], b01.w, acc[r*8+7]);
      acc[r*8+0] = fmaf(a1[r], b10.x, acc[r*8+0]);
      acc[r*8+1] = fmaf(a1[r], b10.y, acc[r*8+1]);
      acc[r*8+2] = fmaf(a1[r], b10.z, acc[r*8+2]);
      acc[r*8+3] = fmaf(a1[r], b10.w, acc[r*8+3]);
      acc[r*8+4] = fmaf(a1[r], b11.x, acc[r*8+4]);
      acc[r*8+5] = fmaf(a1[r], b11.y, acc[r*8+5]);
      acc[r*8+6] = fmaf(a1[r], b11.z, acc[r*8+6]);
      acc[r*8+7] = fmaf(a1[r], b11.w, acc[r*8+7]);
    }
    __syncthreads();   // drains vmcnt(0) -> prefetched buffer ready; cur flips
    cur ^= 1;
  }

  // ------------------- softmax epilogue (rows r0..r0+7 over C=2048) --------
  float* red = lds_a;   // reuse A buffer: [0..63] max partials, [64..127] sums

  // 1) row max: local over 8 cols -> wave shuffle reduce -> cross-wave via LDS
  float m[8];
  #pragma unroll
  for (int r = 0; r < 8; ++r) {
    float v = acc[r*8];
    #pragma unroll
    for (int j = 1; j < 8; ++j) v = fmaxf(v, acc[r*8+j]);
    #pragma unroll
    for (int off = 32; off > 0; off >>= 1) v = fmaxf(v, __shfl_xor(v, off, 64));
    m[r] = v;
  }
  if (lane == 0) {
    #pragma unroll
    for (int r = 0; r < 8; ++r) red[wav * 8 + r] = m[r];
  }
  __syncthreads();
  #pragma unroll
  for (int r = 0; r < 8; ++r) {
    float v =          red[(tr*4+0)*8 + r];
    v = fmaxf(v,       red[(tr*4+1)*8 + r]);
    v = fmaxf(v,       red[(tr*4+2)*8 + r]);
    m[r] = fmaxf(v,    red[(tr*4+3)*8 + r]);
  }

  // 2) exp + row sum
  float l[8];
  #pragma unroll
  for (int r = 0; r < 8; ++r) {
    float s = 0.f;
    #pragma unroll
    for (int j = 0; j < 8; ++j) {
      float e = __expf(acc[r*8+j] - m[r]);
      acc[r*8+j] = e;
      s += e;
    }
    #pragma unroll
    for (int off = 32; off > 0; off >>= 1) s += __shfl_xor(s, off, 64);
    l[r] = s;
  }
  if (lane == 0) {
    #pragma unroll
    for (int r = 0; r < 8; ++r) red[64 + wav * 8 + r] = l[r];
  }
  __syncthreads();

  // 3) normalize + coalesced float4 stores
  #pragma unroll
  for (int r = 0; r < 8; ++r) {
    float s = red[64 + (tr*4+0)*8 + r] + red[64 + (tr*4+1)*8 + r]
            + red[64 + (tr*4+2)*8 + r] + red[64 + (tr*4+3)*8 + r];
    float inv = 1.0f / s;
    float4 o0 = make_float4(acc[r*8+0]*inv, acc[r*8+1]*inv,
                            acc[r*8+2]*inv, acc[r*8+3]*inv);
    float4 o1 = make_float4(acc[r*8+4]*inv, acc[r*8+5]*inv,
                            acc[r*8+6]*inv, acc[r*8+7]*inv);
    float4* orow = (float4*)(out + (size_t)(q0 + r0 + r) * CDIM);
    orow[tc]       = o0;    // cols tc*4..tc*4+3
    orow[256 + tc] = o1;    // cols 1024+tc*4..
  }
}

// ---------------------------------------------------------------------------
extern "C" void kernel_launch(void* const* d_in, const int* in_sizes, int n_in,
                              void* d_out, int out_size, void* d_ws, size_t ws_size,
                              hipStream_t stream) {
  const float* x  = (const float*)d_in[0];   // [16384][512]
  const float* y  = (const float*)d_in[1];   // [2048][5][512]
  float* out      = (float*)d_out;           // [16384][2048]
  float* bt       = (float*)d_ws;            // Bt[512][2048] = 4 MB scratch

  hipLaunchKernelGGL(proto_kernel, dim3(CDIM / 64, DDIM / 64), dim3(256),
                     0, stream, y, bt);
  hipLaunchKernelGGL(gemm_softmax_kernel, dim3(QTOT / QB), dim3(NT),
                     0, stream, x, bt, out);
}

// Round 2
// 314.500 us; speedup vs baseline: 1.8216x; 1.8216x over previous
//
#include <hip/hip_runtime.h>
#include <hip/hip_bf16.h>
#include <math.h>

// Problem: x[16384][512] f32, y[2048][5][512] f32 -> softmax(x @ mean_s(y).T) [16384][2048] f32
#define QTOT 16384
#define CDIM 2048
#define DDIM 512
#define SDIM 5

#define NKT   (DDIM / 32)        // 16 k-tiles of 32
#define NCTG  (CDIM / 16)        // 128 c-tiles of 16
#define MB    32                 // rows per block
#define NT    1024               // 16 waves
#define NWAVE 16
#define CPW   (CDIM / NWAVE)     // 128 cols per wave
#define CTPW  (CPW / 16)         // 8 c-tiles per wave

typedef short  s8v  __attribute__((ext_vector_type(8)));   // 8 bf16 = 4 VGPR (MFMA A/B frag)
typedef float  f32x4 __attribute__((ext_vector_type(4)));  // MFMA C/D frag

// round-to-nearest f32 -> bf16 bits
__device__ __forceinline__ unsigned short f2bf(float f) {
  unsigned int u = __float_as_uint(f);
  return (unsigned short)((u + 0x7FFFu + ((u >> 16) & 1u)) >> 16);
}
__device__ __forceinline__ float bf2f(unsigned short h) {
  return __uint_as_float(((unsigned int)h) << 16);
}

// ---------------------------------------------------------------------------
// Prep: P[c][k] = mean_s y[c][s][k]; split hi/lo bf16; store fragment-major:
//   Bf[kt][ctg][h][lane][j]  (lane = (c&15) + 16*((k&31)>>3), j = k&7)
// so a wave's B-fragment load for (kt,ctg,h) is 64 lanes x 16B contiguous.
__global__ void __launch_bounds__(256)
prep_kernel(const float* __restrict__ y, unsigned short* __restrict__ bf) {
  const int t  = threadIdx.x;
  const int c0 = blockIdx.x * 16;          // 128 blocks x 16 classes
  #pragma unroll
  for (int e = 0; e < 32; ++e) {
    int flat = e * 256 + t;                // 16*512 elements per block
    int cl   = flat >> 9;                  // 0..15
    int k    = flat & 511;
    int c    = c0 + cl;
    const float* p = y + (size_t)c * (SDIM * DDIM) + k;
    float s = 0.f;
    #pragma unroll
    for (int ss = 0; ss < SDIM; ++ss) s += p[ss * DDIM];
    float v  = s * 0.2f;
    unsigned short hi = f2bf(v);
    unsigned short lo = f2bf(v - bf2f(hi));
    int kt   = k >> 5;
    int ctg  = c >> 4;
    int lane = (c & 15) + 16 * ((k & 31) >> 3);
    int j    = k & 7;
    size_t base = ((size_t)(kt * NCTG + ctg) * 2) * 512 + lane * 8 + j;
    bf[base]       = hi;   // h=0
    bf[base + 512] = lo;   // h=1
  }
}

// ---------------------------------------------------------------------------
// Fused GEMM (3-pass bf16 MFMA: hihi + lohi + hilo) + row softmax.
// Block: 32 rows x 2048 cols, 16 waves; wave w owns cols w*128..w*128+127.
// A staged once into LDS fragment-major (64KB, hi+lo). B direct from global
// (4MB, L2-resident, broadcast across blocks). NO barriers in the K-loop.
__global__ void __launch_bounds__(NT)
gemm_softmax_kernel(const float* __restrict__ x,
                    const unsigned short* __restrict__ bf,
                    float* __restrict__ out) {
  __shared__ unsigned short ldsA[32768];   // [kt][mt][h][lane][8] = 64KB exactly

  const int t    = threadIdx.x;
  const int lane = t & 63;
  const int w    = t >> 6;                 // 0..15
  const int q0   = blockIdx.x * MB;

  // ---- stage A: read x rows q0..q0+31 (f32, coalesced), split, frag-layout ----
  {
    const float4* x4 = (const float4*)(x + (size_t)q0 * DDIM);
    #pragma unroll
    for (int i = 0; i < 4; ++i) {
      int idx = t + NT * i;                // 4096 float4 total
      int q   = idx >> 7;                  // 0..31
      int k4  = idx & 127;
      float4 f = x4[(size_t)q * 128 + k4];
      int kt    = k4 >> 3;
      int mt    = q >> 4;
      int lanea = (q & 15) + 16 * ((k4 >> 1) & 3);
      int j0    = (k4 & 1) * 4;
      unsigned short h0 = f2bf(f.x), h1 = f2bf(f.y), h2 = f2bf(f.z), h3 = f2bf(f.w);
      unsigned short l0 = f2bf(f.x - bf2f(h0)), l1 = f2bf(f.y - bf2f(h1));
      unsigned short l2 = f2bf(f.z - bf2f(h2)), l3 = f2bf(f.w - bf2f(h3));
      ushort4* dh = (ushort4*)&ldsA[((kt * 4 + mt * 2 + 0) * 512) + lanea * 8 + j0];
      ushort4* dl = (ushort4*)&ldsA[((kt * 4 + mt * 2 + 1) * 512) + lanea * 8 + j0];
      *dh = make_ushort4(h0, h1, h2, h3);
      *dl = make_ushort4(l0, l1, l2, l3);
    }
  }
  __syncthreads();

  f32x4 acc[2][CTPW];
  #pragma unroll
  for (int mt = 0; mt < 2; ++mt)
    #pragma unroll
    for (int ci = 0; ci < CTPW; ++ci) acc[mt][ci] = (f32x4)0.f;

  const s8v* A8 = (const s8v*)ldsA;        // 16B units
  const s8v* B8 = (const s8v*)bf;

  for (int kt = 0; kt < NKT; ++kt) {
    s8v ah0 = A8[(kt * 4 + 0) * 64 + lane];
    s8v al0 = A8[(kt * 4 + 1) * 64 + lane];
    s8v ah1 = A8[(kt * 4 + 2) * 64 + lane];
    s8v al1 = A8[(kt * 4 + 3) * 64 + lane];
    size_t bbase = ((size_t)(kt * NCTG + w * CTPW) * 2) * 64 + lane;
    #pragma unroll
    for (int ci = 0; ci < CTPW; ++ci) {
      s8v bh = B8[bbase + ci * 128];
      s8v bl = B8[bbase + ci * 128 + 64];
      acc[0][ci] = __builtin_amdgcn_mfma_f32_16x16x32_bf16(ah0, bh, acc[0][ci], 0, 0, 0);
      acc[1][ci] = __builtin_amdgcn_mfma_f32_16x16x32_bf16(ah1, bh, acc[1][ci], 0, 0, 0);
      acc[0][ci] = __builtin_amdgcn_mfma_f32_16x16x32_bf16(al0, bh, acc[0][ci], 0, 0, 0);
      acc[1][ci] = __builtin_amdgcn_mfma_f32_16x16x32_bf16(al1, bh, acc[1][ci], 0, 0, 0);
      acc[0][ci] = __builtin_amdgcn_mfma_f32_16x16x32_bf16(ah0, bl, acc[0][ci], 0, 0, 0);
      acc[1][ci] = __builtin_amdgcn_mfma_f32_16x16x32_bf16(ah1, bl, acc[1][ci], 0, 0, 0);
    }
  }
  __syncthreads();   // all waves done reading ldsA; reuse it for reductions

  // ------------------- softmax over c (rows q0..q0+31) ----------------------
  // C/D layout: col = lane&15 (c), row = (lane>>4)*4 + reg (q within 16-tile).
  float* red = (float*)ldsA;               // [row][wave] max: [0..511]; sum: [512..1023]
  const int g = lane >> 4;                 // lane group
  const int cl = lane & 15;

  float mx[2][4];
  #pragma unroll
  for (int mt = 0; mt < 2; ++mt)
    #pragma unroll
    for (int r = 0; r < 4; ++r) {
      float v = acc[mt][0][r];
      #pragma unroll
      for (int ci = 1; ci < CTPW; ++ci) v = fmaxf(v, acc[mt][ci][r]);
      #pragma unroll
      for (int off = 1; off < 16; off <<= 1) v = fmaxf(v, __shfl_xor(v, off, 64));
      mx[mt][r] = v;
    }
  if (cl == 0) {
    #pragma unroll
    for (int mt = 0; mt < 2; ++mt)
      #pragma unroll
      for (int r = 0; r < 4; ++r) red[(mt * 16 + g * 4 + r) * NWAVE + w] = mx[mt][r];
  }
  __syncthreads();
  #pragma unroll
  for (int mt = 0; mt < 2; ++mt)
    #pragma unroll
    for (int r = 0; r < 4; ++r) {
      float v = red[(mt * 16 + g * 4 + r) * NWAVE + cl];
      #pragma unroll
      for (int off = 1; off < 16; off <<= 1) v = fmaxf(v, __shfl_xor(v, off, 64));
      mx[mt][r] = v;
    }
  __syncthreads();   // done reading max partials before sum overwrites region? (separate region, but keep order clean)

  float sm[2][4];
  #pragma unroll
  for (int mt = 0; mt < 2; ++mt)
    #pragma unroll
    for (int r = 0; r < 4; ++r) {
      float s = 0.f;
      #pragma unroll
      for (int ci = 0; ci < CTPW; ++ci) {
        float e = __expf(acc[mt][ci][r] - mx[mt][r]);
        acc[mt][ci][r] = e;
        s += e;
      }
      #pragma unroll
      for (int off = 1; off < 16; off <<= 1) s += __shfl_xor(s, off, 64);
      sm[mt][r] = s;
    }
  if (cl == 0) {
    #pragma unroll
    for (int mt = 0; mt < 2; ++mt)
      #pragma unroll
      for (int r = 0; r < 4; ++r) red[512 + (mt * 16 + g * 4 + r) * NWAVE + w] = sm[mt][r];
  }
  __syncthreads();

  #pragma unroll
  for (int mt = 0; mt < 2; ++mt)
    #pragma unroll
    for (int r = 0; r < 4; ++r) {
      float s = red[512 + (mt * 16 + g * 4 + r) * NWAVE + cl];
      #pragma unroll
      for (int off = 1; off < 16; off <<= 1) s += __shfl_xor(s, off, 64);
      float inv = 1.0f / s;
      size_t row = (size_t)(q0 + mt * 16 + g * 4 + r) * CDIM + w * CPW + cl;
      #pragma unroll
      for (int ci = 0; ci < CTPW; ++ci)
        out[row + ci * 16] = acc[mt][ci][r] * inv;
    }
}

// ---------------------------------------------------------------------------
extern "C" void kernel_launch(void* const* d_in, const int* in_sizes, int n_in,
                              void* d_out, int out_size, void* d_ws, size_t ws_size,
                              hipStream_t stream) {
  const float* x = (const float*)d_in[0];          // [16384][512]
  const float* y = (const float*)d_in[1];          // [2048][5][512]
  float* out     = (float*)d_out;                  // [16384][2048]
  unsigned short* bf = (unsigned short*)d_ws;      // Bf frag-major, 4MB

  hipLaunchKernelGGL(prep_kernel, dim3(CDIM / 16), dim3(256), 0, stream, y, bf);
  hipLaunchKernelGGL(gemm_softmax_kernel, dim3(QTOT / MB), dim3(NT), 0, stream,
                     x, bf, out);
}

// Round 3
// 265.520 us; speedup vs baseline: 2.1576x; 1.1845x over previous
//
#include <hip/hip_runtime.h>
#include <hip/hip_bf16.h>
#include <math.h>

// Problem: x[16384][512] f32, y[2048][5][512] f32 -> softmax(x @ mean_s(y).T) [16384][2048] f32
#define QTOT 16384
#define CDIM 2048
#define DDIM 512
#define SDIM 5

#define NKT   (DDIM / 32)        // 16 k-tiles of 32
#define NCTG  (CDIM / 16)        // 128 c-tiles of 16
#define MB    32                 // rows per block
#define NT    1024               // 16 waves
#define NWAVE 16
#define CPW   (CDIM / NWAVE)     // 128 cols per wave
#define CTPW  (CPW / 16)         // 8 c-tiles per wave

typedef short  s8v  __attribute__((ext_vector_type(8)));   // 8 bf16 = 4 VGPR (MFMA A/B frag)
typedef float  f32x4 __attribute__((ext_vector_type(4)));  // MFMA C/D frag

// round-to-nearest f32 -> bf16 bits
__device__ __forceinline__ unsigned short f2bf(float f) {
  unsigned int u = __float_as_uint(f);
  return (unsigned short)((u + 0x7FFFu + ((u >> 16) & 1u)) >> 16);
}
__device__ __forceinline__ float bf2f(unsigned short h) {
  return __uint_as_float(((unsigned int)h) << 16);
}

// ---------------------------------------------------------------------------
// Prep: P[c][k] = mean_s y[c][s][k]; split hi/lo bf16; store fragment-major:
//   Bf[kt][ctg][h][lane][j]  (lane = (c&15) + 16*((k&31)>>3), j = k&7)
__global__ void __launch_bounds__(256)
prep_kernel(const float* __restrict__ y, unsigned short* __restrict__ bf) {
  const int t  = threadIdx.x;
  const int c0 = blockIdx.x * 8;           // 256 blocks x 8 classes
  #pragma unroll
  for (int e = 0; e < 16; ++e) {
    int flat = e * 256 + t;                // 8*512 elements per block
    int cl   = flat >> 9;                  // 0..7
    int k    = flat & 511;
    int c    = c0 + cl;
    const float* p = y + (size_t)c * (SDIM * DDIM) + k;
    float s = 0.f;
    #pragma unroll
    for (int ss = 0; ss < SDIM; ++ss) s += p[ss * DDIM];
    float v  = s * 0.2f;
    unsigned short hi = f2bf(v);
    unsigned short lo = f2bf(v - bf2f(hi));
    int kt   = k >> 5;
    int ctg  = c >> 4;
    int lane = (c & 15) + 16 * ((k & 31) >> 3);
    int j    = k & 7;
    size_t base = ((size_t)(kt * NCTG + ctg) * 2) * 512 + lane * 8 + j;
    bf[base]       = hi;   // h=0
    bf[base + 512] = lo;   // h=1
  }
}

// ---------------------------------------------------------------------------
// Fused GEMM (3-pass bf16 MFMA) + row softmax, explicit register pipeline.
// Block: 32 rows x 2048 cols, 16 waves; wave w owns cols w*128..w*128+127.
// A staged once into LDS (64KB frag-major, hi+lo). B direct from global
// (4MB, L2-resident). NO barriers in the K-loop; quarter-granularity
// register double-buffer (P/Q) keeps 4-8 L2 loads in flight under MFMAs.
#define MFMA __builtin_amdgcn_mfma_f32_16x16x32_bf16
// B0=bh[ci], B1=bl[ci], B2=bh[ci+1], B3=bl[ci+1]; 3 passes: hihi, lohi, hilo
#define GRP(ci, B0, B1, B2, B3) \
  acc[0][ci]   = MFMA(ah0, B0, acc[0][ci],   0,0,0); \
  acc[1][ci]   = MFMA(ah1, B0, acc[1][ci],   0,0,0); \
  acc[0][ci]   = MFMA(al0, B0, acc[0][ci],   0,0,0); \
  acc[1][ci]   = MFMA(al1, B0, acc[1][ci],   0,0,0); \
  acc[0][ci]   = MFMA(ah0, B1, acc[0][ci],   0,0,0); \
  acc[1][ci]   = MFMA(ah1, B1, acc[1][ci],   0,0,0); \
  acc[0][ci+1] = MFMA(ah0, B2, acc[0][ci+1], 0,0,0); \
  acc[1][ci+1] = MFMA(ah1, B2, acc[1][ci+1], 0,0,0); \
  acc[0][ci+1] = MFMA(al0, B2, acc[0][ci+1], 0,0,0); \
  acc[1][ci+1] = MFMA(al1, B2, acc[1][ci+1], 0,0,0); \
  acc[0][ci+1] = MFMA(ah0, B3, acc[0][ci+1], 0,0,0); \
  acc[1][ci+1] = MFMA(ah1, B3, acc[1][ci+1], 0,0,0);

#define LOADG(A_, B_, C_, D_, base, ci0) \
  A_ = B8[(base) + (ci0) * 128];       \
  B_ = B8[(base) + (ci0) * 128 + 64];  \
  C_ = B8[(base) + (ci0) * 128 + 128]; \
  D_ = B8[(base) + (ci0) * 128 + 192];

__global__ void __launch_bounds__(NT, 4)
gemm_softmax_kernel(const float* __restrict__ x,
                    const unsigned short* __restrict__ bf,
                    float* __restrict__ out) {
  __shared__ unsigned short ldsA[32768];   // [kt][mt][h][lane][8] = 64KB exactly

  const int t    = threadIdx.x;
  const int lane = t & 63;
  const int w    = t >> 6;                 // 0..15
  const int q0   = blockIdx.x * MB;

  // ---- stage A: read x rows q0..q0+31 (f32, coalesced), split, frag-layout ----
  {
    const float4* x4 = (const float4*)(x + (size_t)q0 * DDIM);
    #pragma unroll
    for (int i = 0; i < 4; ++i) {
      int idx = t + NT * i;                // 4096 float4 total
      int q   = idx >> 7;                  // 0..31
      int k4  = idx & 127;
      float4 f = x4[(size_t)q * 128 + k4];
      int kt    = k4 >> 3;
      int mt    = q >> 4;
      int lanea = (q & 15) + 16 * ((k4 >> 1) & 3);
      int j0    = (k4 & 1) * 4;
      unsigned short h0 = f2bf(f.x), h1 = f2bf(f.y), h2 = f2bf(f.z), h3 = f2bf(f.w);
      unsigned short l0 = f2bf(f.x - bf2f(h0)), l1 = f2bf(f.y - bf2f(h1));
      unsigned short l2 = f2bf(f.z - bf2f(h2)), l3 = f2bf(f.w - bf2f(h3));
      ushort4* dh = (ushort4*)&ldsA[((kt * 4 + mt * 2 + 0) * 512) + lanea * 8 + j0];
      ushort4* dl = (ushort4*)&ldsA[((kt * 4 + mt * 2 + 1) * 512) + lanea * 8 + j0];
      *dh = make_ushort4(h0, h1, h2, h3);
      *dl = make_ushort4(l0, l1, l2, l3);
    }
  }
  __syncthreads();

  f32x4 acc[2][CTPW];
  #pragma unroll
  for (int mt = 0; mt < 2; ++mt)
    #pragma unroll
    for (int ci = 0; ci < CTPW; ++ci) acc[mt][ci] = (f32x4)0.f;

  const s8v* A8 = (const s8v*)ldsA;        // 16B units
  const s8v* B8 = (const s8v*)bf;

  // ---- K-loop: quarter-granularity register pipeline, no barriers ----
  int bb = (w * CTPW) * 2 * 64 + lane;     // B frag index for (kt=0, ci=0, h=0)
  s8v P0, P1, P2, P3, Q0, Q1, Q2, Q3;
  LOADG(P0, P1, P2, P3, bb, 0);            // prologue: group0 of kt0 in flight
  #pragma unroll 1
  for (int kt = 0; kt < NKT; ++kt) {
    const int kb = kt * 4 * 64 + lane;     // A frag base
    s8v ah0 = A8[kb];
    s8v al0 = A8[kb + 64];
    s8v ah1 = A8[kb + 128];
    s8v al1 = A8[kb + 192];
    LOADG(Q0, Q1, Q2, Q3, bb, 2);          // group1 in flight
    GRP(0, P0, P1, P2, P3);                // compute group0
    LOADG(P0, P1, P2, P3, bb, 4);          // group2 in flight
    GRP(2, Q0, Q1, Q2, Q3);                // compute group1
    LOADG(Q0, Q1, Q2, Q3, bb, 6);          // group3 in flight
    GRP(4, P0, P1, P2, P3);                // compute group2
    const int bbn = (((kt + 1) & 15) * NCTG + w * CTPW) * 2 * 64 + lane;
    LOADG(P0, P1, P2, P3, bbn, 0);         // group0 of kt+1 (wraps harmlessly)
    GRP(6, Q0, Q1, Q2, Q3);                // compute group3
    bb = bbn;
  }
  __syncthreads();   // all waves done reading ldsA; reuse it for reductions

  // ------------------- softmax over c (rows q0..q0+31) ----------------------
  // C/D layout: col = lane&15 (c), row = (lane>>4)*4 + reg (q within 16-tile).
  float* red = (float*)ldsA;               // [row][wave] max: [0..511]; sum: [512..1023]
  const int g  = lane >> 4;                // lane group
  const int cl = lane & 15;

  float mx[2][4];
  #pragma unroll
  for (int mt = 0; mt < 2; ++mt)
    #pragma unroll
    for (int r = 0; r < 4; ++r) {
      float v = acc[mt][0][r];
      #pragma unroll
      for (int ci = 1; ci < CTPW; ++ci) v = fmaxf(v, acc[mt][ci][r]);
      #pragma unroll
      for (int off = 1; off < 16; off <<= 1) v = fmaxf(v, __shfl_xor(v, off, 64));
      mx[mt][r] = v;
    }
  if (cl == 0) {
    #pragma unroll
    for (int mt = 0; mt < 2; ++mt)
      #pragma unroll
      for (int r = 0; r < 4; ++r) red[(mt * 16 + g * 4 + r) * NWAVE + w] = mx[mt][r];
  }
  __syncthreads();
  #pragma unroll
  for (int mt = 0; mt < 2; ++mt)
    #pragma unroll
    for (int r = 0; r < 4; ++r) {
      float v = red[(mt * 16 + g * 4 + r) * NWAVE + cl];
      #pragma unroll
      for (int off = 1; off < 16; off <<= 1) v = fmaxf(v, __shfl_xor(v, off, 64));
      mx[mt][r] = v;
    }
  __syncthreads();

  float sm[2][4];
  #pragma unroll
  for (int mt = 0; mt < 2; ++mt)
    #pragma unroll
    for (int r = 0; r < 4; ++r) {
      float s = 0.f;
      #pragma unroll
      for (int ci = 0; ci < CTPW; ++ci) {
        float e = __expf(acc[mt][ci][r] - mx[mt][r]);
        acc[mt][ci][r] = e;
        s += e;
      }
      #pragma unroll
      for (int off = 1; off < 16; off <<= 1) s += __shfl_xor(s, off, 64);
      sm[mt][r] = s;
    }
  if (cl == 0) {
    #pragma unroll
    for (int mt = 0; mt < 2; ++mt)
      #pragma unroll
      for (int r = 0; r < 4; ++r) red[512 + (mt * 16 + g * 4 + r) * NWAVE + w] = sm[mt][r];
  }
  __syncthreads();

  #pragma unroll
  for (int mt = 0; mt < 2; ++mt)
    #pragma unroll
    for (int r = 0; r < 4; ++r) {
      float s = red[512 + (mt * 16 + g * 4 + r) * NWAVE + cl];
      #pragma unroll
      for (int off = 1; off < 16; off <<= 1) s += __shfl_xor(s, off, 64);
      float inv = 1.0f / s;
      size_t row = (size_t)(q0 + mt * 16 + g * 4 + r) * CDIM + w * CPW + cl;
      #pragma unroll
      for (int ci = 0; ci < CTPW; ++ci)
        out[row + ci * 16] = acc[mt][ci][r] * inv;
    }
}

// ---------------------------------------------------------------------------
extern "C" void kernel_launch(void* const* d_in, const int* in_sizes, int n_in,
                              void* d_out, int out_size, void* d_ws, size_t ws_size,
                              hipStream_t stream) {
  const float* x = (const float*)d_in[0];          // [16384][512]
  const float* y = (const float*)d_in[1];          // [2048][5][512]
  float* out     = (float*)d_out;                  // [16384][2048]
  unsigned short* bf = (unsigned short*)d_ws;      // Bf frag-major, 4MB

  hipLaunchKernelGGL(prep_kernel, dim3(256), dim3(256), 0, stream, y, bf);
  hipLaunchKernelGGL(gemm_softmax_kernel, dim3(QTOT / MB), dim3(NT), 0, stream,
                     x, bf, out);
}

// Round 4
// 261.747 us; speedup vs baseline: 2.1887x; 1.0144x over previous
//
#include <hip/hip_runtime.h>
#include <hip/hip_bf16.h>
#include <math.h>

// Problem: x[16384][512] f32, y[2048][5][512] f32 -> softmax(x @ mean_s(y).T) [16384][2048] f32
#define QTOT 16384
#define CDIM 2048
#define DDIM 512
#define SDIM 5

#define NKT   16                 // k-tiles of 32
#define NCTG  128                // c-tiles of 16
#define MB    32                 // rows per block
#define NT    512                // 8 waves
#define NWAVE 8
#define CPW   256                // cols per wave
#define CTPW  16                 // c-tiles per wave

typedef short  s8v   __attribute__((ext_vector_type(8)));  // 8 bf16 (MFMA A/B frag)
typedef float  f32x4 __attribute__((ext_vector_type(4)));  // MFMA C/D frag

__device__ __forceinline__ unsigned short f2bf(float f) {
  unsigned int u = __float_as_uint(f);
  return (unsigned short)((u + 0x7FFFu + ((u >> 16) & 1u)) >> 16);
}
__device__ __forceinline__ float bf2f(unsigned short h) {
  return __uint_as_float(((unsigned int)h) << 16);
}

// ---------------------------------------------------------------------------
// Prep: P[c][k] = mean_s y[c][s][k]; split hi/lo bf16; fragment-major:
//   Bf[kt][ctg][h][lane][j]  (lane = (c&15) + 16*((k&31)>>3), j = k&7)
__global__ void __launch_bounds__(256)
prep_kernel(const float* __restrict__ y, unsigned short* __restrict__ bf) {
  const int t  = threadIdx.x;
  const int c0 = blockIdx.x * 8;           // 256 blocks x 8 classes
  #pragma unroll
  for (int e = 0; e < 16; ++e) {
    int flat = e * 256 + t;
    int cl   = flat >> 9;
    int k    = flat & 511;
    int c    = c0 + cl;
    const float* p = y + (size_t)c * (SDIM * DDIM) + k;
    float s = 0.f;
    #pragma unroll
    for (int ss = 0; ss < SDIM; ++ss) s += p[ss * DDIM];
    float v  = s * 0.2f;
    unsigned short hi = f2bf(v);
    unsigned short lo = f2bf(v - bf2f(hi));
    int kt   = k >> 5;
    int ctg  = c >> 4;
    int lane = (c & 15) + 16 * ((k & 31) >> 3);
    int j    = k & 7;
    size_t base = ((size_t)(kt * NCTG + ctg) * 2) * 512 + lane * 8 + j;
    bf[base]       = hi;
    bf[base + 512] = lo;
  }
}

// ---------------------------------------------------------------------------
#define MFMA __builtin_amdgcn_mfma_f32_16x16x32_bf16
// B0=bh[ci], B1=bl[ci], B2=bh[ci+1], B3=bl[ci+1]; passes: hihi, lohi, hilo
#define GRP(ci, B0, B1, B2, B3) \
  acc[0][ci]   = MFMA(ah0, B0, acc[0][ci],   0,0,0); \
  acc[1][ci]   = MFMA(ah1, B0, acc[1][ci],   0,0,0); \
  acc[0][ci]   = MFMA(al0, B0, acc[0][ci],   0,0,0); \
  acc[1][ci]   = MFMA(al1, B0, acc[1][ci],   0,0,0); \
  acc[0][ci]   = MFMA(ah0, B1, acc[0][ci],   0,0,0); \
  acc[1][ci]   = MFMA(ah1, B1, acc[1][ci],   0,0,0); \
  acc[0][ci+1] = MFMA(ah0, B2, acc[0][ci+1], 0,0,0); \
  acc[1][ci+1] = MFMA(ah1, B2, acc[1][ci+1], 0,0,0); \
  acc[0][ci+1] = MFMA(al0, B2, acc[0][ci+1], 0,0,0); \
  acc[1][ci+1] = MFMA(al1, B2, acc[1][ci+1], 0,0,0); \
  acc[0][ci+1] = MFMA(ah0, B3, acc[0][ci+1], 0,0,0); \
  acc[1][ci+1] = MFMA(ah1, B3, acc[1][ci+1], 0,0,0);

// 4 x 1KB loads: SGPR-uniform base (wb + uniform off) + lane*16 voffset + imm
#define LOADB(A_, B_, C_, D_, off) do {              \
    const char* p_ = wb + (off);                     \
    A_ = *(const s8v*)(p_ + lane16);                 \
    B_ = *(const s8v*)(p_ + lane16 + 1024);          \
    C_ = *(const s8v*)(p_ + lane16 + 2048);          \
    D_ = *(const s8v*)(p_ + lane16 + 3072);          \
  } while (0)

// phase: issue next group's 4 loads (pinned by sched_barrier), then 12 MFMAs
#define PHASE(L0, L1, L2, L3, loff, ci, C0, C1, C2, C3) \
  LOADB(L0, L1, L2, L3, loff);                          \
  __builtin_amdgcn_sched_barrier(0);                    \
  __builtin_amdgcn_s_setprio(1);                        \
  GRP(ci, C0, C1, C2, C3);                              \
  __builtin_amdgcn_s_setprio(0);

// Fused GEMM (3-pass bf16 MFMA) + row softmax. 8 fat waves (256-reg budget):
// wave w owns all 32 rows x cols w*256..w*256+255 (acc 128 f32). B read
// direct from global (L2-resident, contiguous 32KB per wave per kt), with a
// 4-buffer register pipeline at 3-phase load->use distance. No K-loop barriers.
__global__ void __launch_bounds__(NT, 2)
gemm_softmax_kernel(const float* __restrict__ x,
                    const unsigned short* __restrict__ bf,
                    float* __restrict__ out) {
  __shared__ unsigned short ldsA[32768];   // A frags [kt][mt][h][lane][8] = 64KB

  const int t      = threadIdx.x;
  const int lane   = t & 63;
  const int w      = __builtin_amdgcn_readfirstlane(t >> 6);  // wave id, SGPR
  const int lane16 = lane * 16;
  const int q0     = blockIdx.x * MB;

  // ---- stage A: rows q0..q0+31 f32 coalesced -> hi/lo bf16 frag layout ----
  {
    const float4* x4 = (const float4*)(x + (size_t)q0 * DDIM);
    #pragma unroll
    for (int i = 0; i < 8; ++i) {
      int idx = t + NT * i;                // 4096 float4 total
      int q   = idx >> 7;
      int k4  = idx & 127;
      float4 f = x4[(size_t)q * 128 + k4];
      int kt    = k4 >> 3;
      int mt    = q >> 4;
      int lanea = (q & 15) + 16 * ((k4 >> 1) & 3);
      int j0    = (k4 & 1) * 4;
      unsigned short h0 = f2bf(f.x), h1 = f2bf(f.y), h2 = f2bf(f.z), h3 = f2bf(f.w);
      unsigned short l0 = f2bf(f.x - bf2f(h0)), l1 = f2bf(f.y - bf2f(h1));
      unsigned short l2 = f2bf(f.z - bf2f(h2)), l3 = f2bf(f.w - bf2f(h3));
      ushort4* dh = (ushort4*)&ldsA[((kt * 4 + mt * 2 + 0) * 512) + lanea * 8 + j0];
      ushort4* dl = (ushort4*)&ldsA[((kt * 4 + mt * 2 + 1) * 512) + lanea * 8 + j0];
      *dh = make_ushort4(h0, h1, h2, h3);
      *dl = make_ushort4(l0, l1, l2, l3);
    }
  }
  __syncthreads();

  f32x4 acc[2][CTPW];
  #pragma unroll
  for (int mt = 0; mt < 2; ++mt)
    #pragma unroll
    for (int ci = 0; ci < CTPW; ++ci) acc[mt][ci] = (f32x4)0.f;

  const s8v* A8 = (const s8v*)ldsA;
  // wave-uniform byte base for this wave's B column slice (SGPR addressing)
  const char* wb = (const char*)bf + w * 32768;

  s8v P0,P1,P2,P3, Q0,Q1,Q2,Q3, R0,R1,R2,R3, S0,S1,S2,S3;
  unsigned cur = 0, nxt = 262144;          // kt byte bases (kt stride 256KB)
  LOADB(P0,P1,P2,P3, cur + 0);             // kt0 group0 (ci 0-1)
  LOADB(Q0,Q1,Q2,Q3, cur + 4096);          // kt0 group1 (ci 2-3)
  LOADB(R0,R1,R2,R3, cur + 8192);          // kt0 group2 (ci 4-5)

  #pragma unroll 1
  for (int kt = 0; kt < NKT; ++kt) {
    const int kb = kt * 4 * 64 + lane;     // A frag base for this kt
    s8v ah0 = A8[kb];
    s8v al0 = A8[kb + 64];
    s8v ah1 = A8[kb + 128];
    s8v al1 = A8[kb + 192];
    PHASE(S0,S1,S2,S3, cur + 12288,  0, P0,P1,P2,P3);   // load g3,  use g0
    PHASE(P0,P1,P2,P3, cur + 16384,  2, Q0,Q1,Q2,Q3);   // load g4,  use g1
    PHASE(Q0,Q1,Q2,Q3, cur + 20480,  4, R0,R1,R2,R3);   // load g5,  use g2
    PHASE(R0,R1,R2,R3, cur + 24576,  6, S0,S1,S2,S3);   // load g6,  use g3
    PHASE(S0,S1,S2,S3, cur + 28672,  8, P0,P1,P2,P3);   // load g7,  use g4
    PHASE(P0,P1,P2,P3, nxt + 0,     10, Q0,Q1,Q2,Q3);   // load g0', use g5
    PHASE(Q0,Q1,Q2,Q3, nxt + 4096,  12, R0,R1,R2,R3);   // load g1', use g6
    PHASE(R0,R1,R2,R3, nxt + 8192,  14, S0,S1,S2,S3);   // load g2', use g7
    cur = nxt;
    nxt = (unsigned)((kt + 2) & 15) * 262144u;          // wrap: safe dead loads
  }
  __syncthreads();   // done reading ldsA; reuse for softmax reductions

  // ------------------- softmax over c (rows q0..q0+31) ----------------------
  // C/D layout: col = lane&15, row = (lane>>4)*4 + reg
  float* red = (float*)ldsA;               // [row][wave]: max [0..255], sum [256..511]
  const int g  = lane >> 4;
  const int cl = lane & 15;

  float mx[2][4];
  #pragma unroll
  for (int mt = 0; mt < 2; ++mt)
    #pragma unroll
    for (int r = 0; r < 4; ++r) {
      float v = acc[mt][0][r];
      #pragma unroll
      for (int ci = 1; ci < CTPW; ++ci) v = fmaxf(v, acc[mt][ci][r]);
      #pragma unroll
      for (int off = 1; off < 16; off <<= 1) v = fmaxf(v, __shfl_xor(v, off, 64));
      mx[mt][r] = v;
    }
  if (cl == 0) {
    #pragma unroll
    for (int mt = 0; mt < 2; ++mt)
      #pragma unroll
      for (int r = 0; r < 4; ++r) red[(mt * 16 + g * 4 + r) * NWAVE + w] = mx[mt][r];
  }
  __syncthreads();
  #pragma unroll
  for (int mt = 0; mt < 2; ++mt)
    #pragma unroll
    for (int r = 0; r < 4; ++r) {
      float v = red[(mt * 16 + g * 4 + r) * NWAVE + (cl & 7)];
      #pragma unroll
      for (int off = 1; off < 8; off <<= 1) v = fmaxf(v, __shfl_xor(v, off, 64));
      mx[mt][r] = v;
    }
  __syncthreads();

  float sm[2][4];
  #pragma unroll
  for (int mt = 0; mt < 2; ++mt)
    #pragma unroll
    for (int r = 0; r < 4; ++r) {
      float s = 0.f;
      #pragma unroll
      for (int ci = 0; ci < CTPW; ++ci) {
        float e = __expf(acc[mt][ci][r] - mx[mt][r]);
        acc[mt][ci][r] = e;
        s += e;
      }
      #pragma unroll
      for (int off = 1; off < 16; off <<= 1) s += __shfl_xor(s, off, 64);
      sm[mt][r] = s;
    }
  if (cl == 0) {
    #pragma unroll
    for (int mt = 0; mt < 2; ++mt)
      #pragma unroll
      for (int r = 0; r < 4; ++r) red[256 + (mt * 16 + g * 4 + r) * NWAVE + w] = sm[mt][r];
  }
  __syncthreads();

  #pragma unroll
  for (int mt = 0; mt < 2; ++mt)
    #pragma unroll
    for (int r = 0; r < 4; ++r) {
      float s = red[256 + (mt * 16 + g * 4 + r) * NWAVE + (cl & 7)];
      #pragma unroll
      for (int off = 1; off < 8; off <<= 1) s += __shfl_xor(s, off, 64);
      float inv = 1.0f / s;
      size_t row = (size_t)(q0 + mt * 16 + g * 4 + r) * CDIM + w * CPW + cl;
      #pragma unroll
      for (int ci = 0; ci < CTPW; ++ci)
        out[row + ci * 16] = acc[mt][ci][r] * inv;
    }
}

// ---------------------------------------------------------------------------
extern "C" void kernel_launch(void* const* d_in, const int* in_sizes, int n_in,
                              void* d_out, int out_size, void* d_ws, size_t ws_size,
                              hipStream_t stream) {
  const float* x = (const float*)d_in[0];          // [16384][512]
  const float* y = (const float*)d_in[1];          // [2048][5][512]
  float* out     = (float*)d_out;                  // [16384][2048]
  unsigned short* bf = (unsigned short*)d_ws;      // Bf frag-major, 4MB

  hipLaunchKernelGGL(prep_kernel, dim3(256), dim3(256), 0, stream, y, bf);
  hipLaunchKernelGGL(gemm_softmax_kernel, dim3(QTOT / MB), dim3(NT), 0, stream,
                     x, bf, out);
}